// Round 6
// baseline (299.812 us; speedup 1.0000x reference)
//
#include <hip/hip_runtime.h>
#include <float.h>

#define NUM_EMB 512
#define DIM     128
#define HWX     4096          // 64*64 spatial per batch
#define NPOS    (32 * 4096)   // 131072 positions
#define MARGIN  0.35f         // fp16 noise (13+ sigma) + packed-score quantization (0.064)

// ---------------- workspace layout (bytes) ----------------
#define WS_ZT    ((size_t)0)                    // 131072*128 fp16 = 33554432
#define WS_E16   ((size_t)33554432)             // 512*128 fp16   = 131072
#define WS_ESQ   ((size_t)33685504)             // 512 fp32       = 2048
#define WS_GIDX  ((size_t)33687552)             // (unused in fast path)
#define WS_WL    ((size_t)34211840)             // 131072 int     = 524288
#define WS_CNT   ((size_t)34736128)             // counter        = 256
#define WS_NEED  ((size_t)34736384)

using half8 = __attribute__((ext_vector_type(8))) _Float16;
using f32x4 = __attribute__((ext_vector_type(4))) float;

// ---------------- prep: e16[k][c], exact e_sq, zero counter ----------------
__global__ void prep_kernel(const float* __restrict__ emb, _Float16* __restrict__ e16,
                            float* __restrict__ esq, int* __restrict__ cnt) {
    int k = blockIdx.x * blockDim.x + threadIdx.x;
    if (k == 0) *cnt = 0;
    if (k < NUM_EMB) {
        const float4* row = (const float4*)(emb + (size_t)k * DIM);
        _Float16* dst = e16 + (size_t)k * DIM;
        float s0 = 0.f, s1 = 0.f, s2 = 0.f, s3 = 0.f;
        #pragma unroll
        for (int c = 0; c < DIM / 4; ++c) {
            float4 v = row[c];
            s0 = fmaf(v.x, v.x, s0);
            s1 = fmaf(v.y, v.y, s1);
            s2 = fmaf(v.z, v.z, s2);
            s3 = fmaf(v.w, v.w, s3);
            dst[4 * c + 0] = (_Float16)v.x;
            dst[4 * c + 1] = (_Float16)v.y;
            dst[4 * c + 2] = (_Float16)v.z;
            dst[4 * c + 3] = (_Float16)v.w;
        }
        esq[k] = (s0 + s1) + (s2 + s3);   // identical math to round-1 (verified exact vs numpy)
    }
}

// ---------------- transpose: z (b,c,hw) fp32 -> zt (n,c) fp16 ----------------
__global__ __launch_bounds__(256) void transpose_kernel(const float* __restrict__ z,
                                                        _Float16* __restrict__ zt) {
    __shared__ __align__(16) _Float16 sh[64 * 136];   // 64 rows, 272B stride (pad 16B)
    int t = threadIdx.x;
    int n0 = blockIdx.x * 64;
    int b = n0 >> 12, hw0 = n0 & 4095;
    int q = t >> 6, l = t & 63;
    const float* src = z + (size_t)b * DIM * HWX + hw0 + l;
    #pragma unroll
    for (int i = 0; i < 32; ++i) {
        int c = q * 32 + i;
        float v = src[(size_t)c * HWX];           // 64 consecutive lanes -> coalesced
        sh[l * 136 + c] = (_Float16)v;
    }
    __syncthreads();
    #pragma unroll
    for (int r = 0; r < 4; ++r) {
        int f = r * 4096 + t * 16;                // byte offset in 16KB output tile
        int row = f >> 8, colb = f & 255;
        float4 v = *(const float4*)((const char*)sh + row * 272 + colb);
        *(float4*)((char*)(zt + (size_t)(n0 + row) * DIM) + colb) = v;  // contiguous writes
    }
}

// ---------------- gemm v3: LDS-A (single barrier), streaming-B, fused out-write --
// Block = 128 pos x 512 codes, 4 waves (wm,wn in {0,1}); wave = 64 pos x 32
// codes per 64-code tile. A staged to LDS ONCE (32KB, 1 barrier), fragments
// re-read per tile via ds_read_b128 (b128-floor cost). B streams global->reg
// from 128KB L2-hot e16 -- no barrier in K-loop, no persistent A regs ->
// VGPR<=128 (launch_bounds(256,4)) -> 16 waves/CU. Scores packed
// (score&~511)|code; winner row written directly to out (gather fused).
__global__ __launch_bounds__(256, 4) void gemm_argmin(const _Float16* __restrict__ zt,
                                                      const _Float16* __restrict__ e16,
                                                      const float* __restrict__ esq,
                                                      const float* __restrict__ emb,
                                                      float* __restrict__ out,
                                                      int* __restrict__ wl,
                                                      int* __restrict__ cnt) {
    __shared__ __align__(16) char Ash[128 * 272];   // 128 pos rows, 272B stride
    __shared__ float mB1[2][128];
    __shared__ float mB2[2][128];
    __shared__ int   ish[128];

    int t = threadIdx.x;
    int lane = t & 63, wave = t >> 6;
    int wm = wave & 1, wn = wave >> 1;
    int quad = lane >> 4, l15 = lane & 15;
    int n0 = blockIdx.x * 128;

    // ---- stage A once: zt rows n0..n0+127 (contiguous 32KB) -> padded LDS
    {
        const char* src = (const char*)zt + ((size_t)n0 << 8);
        #pragma unroll
        for (int r = 0; r < 8; ++r) {
            int f = r * 4096 + t * 16;
            int row = f >> 8, colb = f & 255;
            float4 v = *(const float4*)(src + f);
            *(float4*)(Ash + row * 272 + colb) = v;
        }
    }
    __syncthreads();   // the ONLY barrier before the epilogue

    float b1[16], b2[16];
    #pragma unroll
    for (int s = 0; s < 16; ++s) { b1[s] = 3.0e38f; b2[s] = 3.0e38f; }

    // A-fragment LDS base: row = wm*64 + mt*16 + l15, byte = kc*64 + quad*16
    const char* abase = Ash + (wm * 64 + l15) * 272 + quad * 16;
    const char* ebase = (const char*)e16 + ((size_t)(wn * 32 + l15) << 8) + quad * 16;
    const float* eqb  = esq + wn * 32 + l15;

    for (int tile = 0; tile < 8; ++tile) {
        // ---- B fragments: 8 dwordx4 from L2-hot e16, issued together
        half8 bf[2][4];
        {
            const char* eb = ebase + (size_t)tile * 64 * 256;
            #pragma unroll
            for (int nt = 0; nt < 2; ++nt)
                #pragma unroll
                for (int kc = 0; kc < 4; ++kc)
                    bf[nt][kc] = *(const half8*)(eb + nt * 4096 + kc * 64);
        }
        float es0 = eqb[tile * 64];
        float es1 = eqb[tile * 64 + 16];

        f32x4 acc[4][2];
        #pragma unroll
        for (int mt = 0; mt < 4; ++mt)
            #pragma unroll
            for (int nt = 0; nt < 2; ++nt)
                acc[mt][nt] = (f32x4){0.f, 0.f, 0.f, 0.f};

        #pragma unroll
        for (int kc = 0; kc < 4; ++kc) {
            half8 af[4];
            #pragma unroll
            for (int mt = 0; mt < 4; ++mt)
                af[mt] = *(const half8*)(abase + mt * 16 * 272 + kc * 64);
            #pragma unroll
            for (int mt = 0; mt < 4; ++mt)
                #pragma unroll
                for (int nt = 0; nt < 2; ++nt)
                    acc[mt][nt] = __builtin_amdgcn_mfma_f32_16x16x32_f16(af[mt], bf[nt][kc], acc[mt][nt], 0, 0, 0);
        }

        // ---- packed top-2: ~6 VALU/score, index rides in the low 9 bits
        #pragma unroll
        for (int nt = 0; nt < 2; ++nt) {
            unsigned code = (unsigned)(tile * 64 + wn * 32 + nt * 16 + l15);
            float es = nt ? es1 : es0;
            #pragma unroll
            for (int mt = 0; mt < 4; ++mt)
                #pragma unroll
                for (int r = 0; r < 4; ++r) {
                    int s = mt * 4 + r;
                    float sc = fmaf(-2.0f, acc[mt][nt][r], es);
                    float p = __uint_as_float((__float_as_uint(sc) & 0xFFFFFE00u) | code);
                    b2[s] = fminf(b2[s], fmaxf(b1[s], p));
                    b1[s] = fminf(b1[s], p);
                }
        }
    }

    // ---- butterfly top-2 merge across the 16 lanes (l15) sharing each position
    #pragma unroll
    for (int d = 1; d < 16; d <<= 1) {
        #pragma unroll
        for (int s = 0; s < 16; ++s) {
            float ob1 = __shfl_xor(b1[s], d, 64);
            float ob2 = __shfl_xor(b2[s], d, 64);
            b2[s] = fminf(fminf(b2[s], ob2), fmaxf(b1[s], ob1));
            b1[s] = fminf(b1[s], ob1);
        }
    }
    if (l15 == 0) {
        #pragma unroll
        for (int s = 0; s < 16; ++s) {
            int m = wm * 64 + (s >> 2) * 16 + quad * 4 + (s & 3);
            mB1[wn][m] = b1[s];
            mB2[wn][m] = b2[s];
        }
    }
    __syncthreads();
    if (t < 128) {
        float a1 = mB1[0][t], c1 = mB1[1][t];
        float f1 = fminf(a1, c1);
        float f2 = fminf(fminf(mB2[0][t], mB2[1][t]), fmaxf(a1, c1));
        ish[t] = (int)(__float_as_uint(f1) & 511u);
        if (f2 - f1 < MARGIN) {
            int p = atomicAdd(cnt, 1);
            wl[p] = n0 + t;
        }
    }
    __syncthreads();

    // ---- fused gather: 2 threads per position, winner row from L2-hot emb
    {
        int p = t >> 1, half = t & 1;
        int n = n0 + p;
        int b = n >> 12, hw = n & 4095;
        int idx = ish[p];
        const float4* sel = (const float4*)(emb + (size_t)idx * DIM) + half * 16;
        float* ob = out + (size_t)b * DIM * HWX + (size_t)half * 64 * HWX + hw;
        #pragma unroll
        for (int c4 = 0; c4 < 16; ++c4) {
            float4 v = sel[c4];
            ob[(size_t)(4 * c4 + 0) * HWX] = v.x;
            ob[(size_t)(4 * c4 + 1) * HWX] = v.y;
            ob[(size_t)(4 * c4 + 2) * HWX] = v.z;
            ob[(size_t)(4 * c4 + 3) * HWX] = v.w;
        }
    }
}

// ---------------- refine v4: exact rescan of flagged positions, writes out rows --
__global__ __launch_bounds__(256) void refine_kernel(const float* __restrict__ z,
                                                     const float* __restrict__ emb,
                                                     const float* __restrict__ esq,
                                                     const int* __restrict__ wl,
                                                     const int* __restrict__ cnt,
                                                     float* __restrict__ out) {
    __shared__ __align__(16) float zsh[64][132];   // [entry][dim]
    __shared__ __align__(16) float esh[64][132];   // [code][dim], col 128 = esq
    __shared__ float rs[64][16];
    __shared__ int   ri[64][16];
    __shared__ int   nsh[64];
    __shared__ int   ksh[64];

    int t = threadIdx.x, lane = t & 63, wave = t >> 6;
    int te = t & 15, tc = t >> 4;                  // entry group / code group
    int count = *cnt;

    for (int base = blockIdx.x * 64; base < count; base += 256 * 64) {
        for (int j16 = 0; j16 < 16; ++j16) {
            int e = wave * 16 + j16;
            int ge = base + e;
            if (ge > count - 1) ge = count - 1;    // clamp: duplicate entries benign
            int n = wl[ge];
            if (lane == 0) nsh[e] = n;
            int b = n >> 12, hw = n & 4095;
            const float* zp = z + (size_t)b * DIM * HWX + hw;
            zsh[e][lane]      = zp[(size_t)lane * HWX];
            zsh[e][lane + 64] = zp[(size_t)(lane + 64) * HWX];
        }

        float best[4]; int bi[4];
        #pragma unroll
        for (int i = 0; i < 4; ++i) { best[i] = 3.0e38f; bi[i] = 0; }

        for (int tile = 0; tile < 8; ++tile) {
            __syncthreads();    // zsh/nsh ready (tile 0); prev esh reads done (tile>0)
            {   // stage 64 codes x 128 dims fp32, coalesced b128; esq into col 128
                const float4* gsrc = (const float4*)(emb + (size_t)tile * 64 * DIM);
                #pragma unroll
                for (int jj = 0; jj < 8; ++jj) {
                    int f = jj * 256 + t;
                    int k = f >> 5, q = f & 31;
                    float4 v = gsrc[f];
                    *(float4*)&esh[k][q * 4] = v;
                }
                if (t < 64) esh[t][128] = esq[tile * 64 + t];
            }
            __syncthreads();

            float acc[4][4];
            #pragma unroll
            for (int i = 0; i < 4; ++i)
                #pragma unroll
                for (int j = 0; j < 4; ++j) acc[i][j] = 0.f;

            #pragma unroll 4
            for (int c4 = 0; c4 < 32; ++c4) {
                float4 zv[4], ev[4];
                #pragma unroll
                for (int i = 0; i < 4; ++i) zv[i] = *(const float4*)&zsh[te + 16 * i][c4 * 4];
                #pragma unroll
                for (int j = 0; j < 4; ++j) ev[j] = *(const float4*)&esh[tc * 4 + j][c4 * 4];
                #pragma unroll
                for (int i = 0; i < 4; ++i)
                    #pragma unroll
                    for (int j = 0; j < 4; ++j) {
                        acc[i][j] = fmaf(zv[i].x, ev[j].x, acc[i][j]);
                        acc[i][j] = fmaf(zv[i].y, ev[j].y, acc[i][j]);
                        acc[i][j] = fmaf(zv[i].z, ev[j].z, acc[i][j]);
                        acc[i][j] = fmaf(zv[i].w, ev[j].w, acc[i][j]);
                    }
            }
            #pragma unroll
            for (int j = 0; j < 4; ++j) {
                int k = tile * 64 + tc * 4 + j;
                float es = esh[tc * 4 + j][128];
                #pragma unroll
                for (int i = 0; i < 4; ++i) {
                    float s = fmaf(-2.f, acc[i][j], es);
                    if (s < best[i]) { best[i] = s; bi[i] = k; }  // k ascending per thread
                }
            }
        }
        __syncthreads();   // all esh/zsh reads done
        #pragma unroll
        for (int i = 0; i < 4; ++i) { rs[te + 16 * i][tc] = best[i]; ri[te + 16 * i][tc] = bi[i]; }
        __syncthreads();
        if (t < 64) {
            float bs = rs[t][0]; int bk = ri[t][0];
            #pragma unroll
            for (int q = 1; q < 16; ++q) {     // lex (s,k): first-min over all 512 codes
                float s2 = rs[t][q]; int k2 = ri[t][q];
                bool take = (s2 < bs) || (s2 == bs && k2 < bk);
                bs = take ? s2 : bs;
                bk = take ? k2 : bk;
            }
            ksh[t] = bk;
        }
        __syncthreads();
        {   // write corrected rows: 4 threads per entry x 32 dims
            int e = t >> 2, qq = t & 3;
            int n = nsh[e];
            int b = n >> 12, hw = n & 4095;
            int kk = ksh[e];
            const float4* sel = (const float4*)(emb + (size_t)kk * DIM) + qq * 8;
            float* ob = out + (size_t)b * DIM * HWX + (size_t)qq * 32 * HWX + hw;
            #pragma unroll
            for (int c4 = 0; c4 < 8; ++c4) {
                float4 v = sel[c4];
                ob[(size_t)(4 * c4 + 0) * HWX] = v.x;
                ob[(size_t)(4 * c4 + 1) * HWX] = v.y;
                ob[(size_t)(4 * c4 + 2) * HWX] = v.z;
                ob[(size_t)(4 * c4 + 3) * HWX] = v.w;
            }
        }
        __syncthreads();   // protect zsh/nsh/ksh for next grid-stride round
    }
}

// ---------------- legacy fallback (round-1, verified) ----------------
__global__ void esq_kernel(const float* __restrict__ emb, float* __restrict__ e_sq) {
    int k = blockIdx.x * blockDim.x + threadIdx.x;
    if (k < NUM_EMB) {
        const float4* row = (const float4*)(emb + k * DIM);
        float s0 = 0.f, s1 = 0.f, s2 = 0.f, s3 = 0.f;
        #pragma unroll
        for (int c = 0; c < DIM / 4; ++c) {
            float4 v = row[c];
            s0 = fmaf(v.x, v.x, s0); s1 = fmaf(v.y, v.y, s1);
            s2 = fmaf(v.z, v.z, s2); s3 = fmaf(v.w, v.w, s3);
        }
        e_sq[k] = (s0 + s1) + (s2 + s3);
    }
}

__global__ __launch_bounds__(256) void vq_kernel(const float* __restrict__ z,
                                                 const float* __restrict__ emb,
                                                 const float* __restrict__ e_sq,
                                                 float* __restrict__ out) {
    int n = blockIdx.x * 256 + threadIdx.x;
    int b = n >> 12, hw = n & 4095;
    const float* zb = z + (size_t)b * DIM * HWX + hw;
    float zr[DIM];
    #pragma unroll
    for (int c = 0; c < DIM; ++c) zr[c] = zb[(size_t)c * HWX];
    float best = FLT_MAX; int besti = 0;
    for (int k = 0; k < NUM_EMB; ++k) {
        const float4* er = (const float4*)(emb + k * DIM);
        float d0 = 0.f, d1 = 0.f, d2 = 0.f, d3 = 0.f;
        #pragma unroll
        for (int c = 0; c < DIM / 4; ++c) {
            float4 e = er[c];
            d0 = fmaf(zr[4 * c + 0], e.x, d0);
            d1 = fmaf(zr[4 * c + 1], e.y, d1);
            d2 = fmaf(zr[4 * c + 2], e.z, d2);
            d3 = fmaf(zr[4 * c + 3], e.w, d3);
        }
        float s = e_sq[k] - 2.f * ((d0 + d1) + (d2 + d3));
        if (s < best) { best = s; besti = k; }
    }
    float* ob = out + (size_t)b * DIM * HWX + hw;
    const float4* sel = (const float4*)(emb + (size_t)besti * DIM);
    #pragma unroll
    for (int c4 = 0; c4 < DIM / 4; ++c4) {
        float4 v = sel[c4];
        ob[(size_t)(4 * c4 + 0) * HWX] = v.x;
        ob[(size_t)(4 * c4 + 1) * HWX] = v.y;
        ob[(size_t)(4 * c4 + 2) * HWX] = v.z;
        ob[(size_t)(4 * c4 + 3) * HWX] = v.w;
    }
}

extern "C" void kernel_launch(void* const* d_in, const int* in_sizes, int n_in,
                              void* d_out, int out_size, void* d_ws, size_t ws_size,
                              hipStream_t stream) {
    const float* z   = (const float*)d_in[0];   // (32,128,64,64) fp32
    const float* emb = (const float*)d_in[1];   // (512,128) fp32
    float* out = (float*)d_out;

    if (ws_size < WS_NEED) {
        // fallback: verified round-1 path
        float* e_sq = (float*)d_ws;
        esq_kernel<<<(NUM_EMB + 255) / 256, 256, 0, stream>>>(emb, e_sq);
        vq_kernel<<<NPOS / 256, 256, 0, stream>>>(z, emb, e_sq, out);
        return;
    }

    char* ws = (char*)d_ws;
    _Float16* zt  = (_Float16*)(ws + WS_ZT);
    _Float16* e16 = (_Float16*)(ws + WS_E16);
    float*    esq = (float*)(ws + WS_ESQ);
    int*      wl   = (int*)(ws + WS_WL);
    int*      cnt  = (int*)(ws + WS_CNT);

    prep_kernel<<<2, 256, 0, stream>>>(emb, e16, esq, cnt);
    transpose_kernel<<<NPOS / 64, 256, 0, stream>>>(z, zt);
    gemm_argmin<<<NPOS / 128, 256, 0, stream>>>(zt, e16, esq, emb, out, wl, cnt);
    refine_kernel<<<256, 256, 0, stream>>>(z, emb, esq, wl, cnt, out);
}

// Round 7
// 243.527 us; speedup vs baseline: 1.2311x; 1.2311x over previous
//
#include <hip/hip_runtime.h>
#include <float.h>

#define NUM_EMB 512
#define DIM     128
#define HWX     4096          // 64*64 spatial per batch
#define NPOS    (32 * 4096)   // 131072 positions
#define MARGIN  0.35f         // fp16 noise (13+ sigma) + packed-score quantization (0.064)

// ---------------- workspace layout (bytes) ----------------
#define WS_E16   ((size_t)33554432)             // 512*128 fp16   = 131072
#define WS_ESQ   ((size_t)33685504)             // 512 fp32       = 2048
#define WS_WL    ((size_t)34211840)             // 131072 int     = 524288
#define WS_CNT   ((size_t)34736128)             // counter        = 256
#define WS_NEED  ((size_t)34736384)

using half8 = __attribute__((ext_vector_type(8))) _Float16;
using f32x4 = __attribute__((ext_vector_type(4))) float;

// ---------------- prep: e16[k][c], exact e_sq, zero counter ----------------
__global__ void prep_kernel(const float* __restrict__ emb, _Float16* __restrict__ e16,
                            float* __restrict__ esq, int* __restrict__ cnt) {
    int k = blockIdx.x * blockDim.x + threadIdx.x;
    if (k == 0) *cnt = 0;
    if (k < NUM_EMB) {
        const float4* row = (const float4*)(emb + (size_t)k * DIM);
        _Float16* dst = e16 + (size_t)k * DIM;
        float s0 = 0.f, s1 = 0.f, s2 = 0.f, s3 = 0.f;
        #pragma unroll
        for (int c = 0; c < DIM / 4; ++c) {
            float4 v = row[c];
            s0 = fmaf(v.x, v.x, s0);
            s1 = fmaf(v.y, v.y, s1);
            s2 = fmaf(v.z, v.z, s2);
            s3 = fmaf(v.w, v.w, s3);
            dst[4 * c + 0] = (_Float16)v.x;
            dst[4 * c + 1] = (_Float16)v.y;
            dst[4 * c + 2] = (_Float16)v.z;
            dst[4 * c + 3] = (_Float16)v.w;
        }
        esq[k] = (s0 + s1) + (s2 + s3);   // identical math to round-1 (verified exact vs numpy)
    }
}

// ---------------- gemm v4: fused z-load, LDS-A (1 barrier), streaming-B, fused write
// Block = 128 pos x 512 codes, 4 waves (wm,wn in {0,1}); wave = 64 pos x 32
// codes per 64-code tile. Prologue gathers z directly (no transpose kernel, no
// zt round-trip): thread = (pos, half-row); per channel, lanes read two 128B
// contiguous segments (coalesced); fp32->fp16 in regs; 8 ds_write_b128 into
// the 272B-stride A-layout (2 lanes/bank-group free; 8 acc/bank = b128 floor).
// One barrier. B streams global->reg from 128KB L2-hot e16 -- no barrier in
// the K-loop. NO launch_bounds waves hint: round-6's (256,4) made the
// allocator pick 64 VGPRs and spill b1/b2 to scratch (FETCH 17->194 MB).
// Scores packed (score&~511)|code; winner row written directly to out.
__global__ __launch_bounds__(256) void gemm_argmin(const float* __restrict__ z,
                                                   const _Float16* __restrict__ e16,
                                                   const float* __restrict__ esq,
                                                   const float* __restrict__ emb,
                                                   float* __restrict__ out,
                                                   int* __restrict__ wl,
                                                   int* __restrict__ cnt) {
    __shared__ __align__(16) char Ash[128 * 272];   // 128 pos rows, 272B stride
    __shared__ float mB1[2][128];
    __shared__ float mB2[2][128];
    __shared__ int   ish[128];

    int t = threadIdx.x;
    int lane = t & 63, wave = t >> 6;
    int wm = wave & 1, wn = wave >> 1;
    int quad = lane >> 4, l15 = lane & 15;
    int n0 = blockIdx.x * 128;

    // ---- fused transpose: gather z, convert, stage A to LDS
    {
        int p = t >> 1, h = t & 1;                 // position / channel-half
        int n = n0 + p;
        int b = n >> 12, hw = n & 4095;
        const float* zp = z + (size_t)b * DIM * HWX + (size_t)h * 64 * HWX + hw;
        char* arow = Ash + p * 272 + h * 128;
        #pragma unroll
        for (int cc = 0; cc < 8; ++cc) {
            float v[8];
            #pragma unroll
            for (int j = 0; j < 8; ++j) v[j] = zp[(size_t)(cc * 8 + j) * HWX];
            half8 hv;
            #pragma unroll
            for (int j = 0; j < 8; ++j) hv[j] = (_Float16)v[j];
            *(half8*)(arow + cc * 16) = hv;
        }
    }
    __syncthreads();   // the ONLY barrier before the epilogue

    float b1[16], b2[16];
    #pragma unroll
    for (int s = 0; s < 16; ++s) { b1[s] = 3.0e38f; b2[s] = 3.0e38f; }

    // A-fragment LDS base: row = wm*64 + mt*16 + l15, byte = kc*64 + quad*16
    const char* abase = Ash + (wm * 64 + l15) * 272 + quad * 16;
    const char* ebase = (const char*)e16 + ((size_t)(wn * 32 + l15) << 8) + quad * 16;
    const float* eqb  = esq + wn * 32 + l15;

    for (int tile = 0; tile < 8; ++tile) {
        // ---- B fragments: 8 dwordx4 from L2-hot e16, issued together
        half8 bf[2][4];
        {
            const char* eb = ebase + (size_t)tile * 64 * 256;
            #pragma unroll
            for (int nt = 0; nt < 2; ++nt)
                #pragma unroll
                for (int kc = 0; kc < 4; ++kc)
                    bf[nt][kc] = *(const half8*)(eb + nt * 4096 + kc * 64);
        }
        float es0 = eqb[tile * 64];
        float es1 = eqb[tile * 64 + 16];

        f32x4 acc[4][2];
        #pragma unroll
        for (int mt = 0; mt < 4; ++mt)
            #pragma unroll
            for (int nt = 0; nt < 2; ++nt)
                acc[mt][nt] = (f32x4){0.f, 0.f, 0.f, 0.f};

        #pragma unroll
        for (int kc = 0; kc < 4; ++kc) {
            half8 af[4];
            #pragma unroll
            for (int mt = 0; mt < 4; ++mt)
                af[mt] = *(const half8*)(abase + mt * 16 * 272 + kc * 64);
            #pragma unroll
            for (int mt = 0; mt < 4; ++mt)
                #pragma unroll
                for (int nt = 0; nt < 2; ++nt)
                    acc[mt][nt] = __builtin_amdgcn_mfma_f32_16x16x32_f16(af[mt], bf[nt][kc], acc[mt][nt], 0, 0, 0);
        }

        // ---- packed top-2: ~6 VALU/score, index rides in the low 9 bits
        #pragma unroll
        for (int nt = 0; nt < 2; ++nt) {
            unsigned code = (unsigned)(tile * 64 + wn * 32 + nt * 16 + l15);
            float es = nt ? es1 : es0;
            #pragma unroll
            for (int mt = 0; mt < 4; ++mt)
                #pragma unroll
                for (int r = 0; r < 4; ++r) {
                    int s = mt * 4 + r;
                    float sc = fmaf(-2.0f, acc[mt][nt][r], es);
                    float p = __uint_as_float((__float_as_uint(sc) & 0xFFFFFE00u) | code);
                    b2[s] = fminf(b2[s], fmaxf(b1[s], p));
                    b1[s] = fminf(b1[s], p);
                }
        }
    }

    // ---- butterfly top-2 merge across the 16 lanes (l15) sharing each position
    #pragma unroll
    for (int d = 1; d < 16; d <<= 1) {
        #pragma unroll
        for (int s = 0; s < 16; ++s) {
            float ob1 = __shfl_xor(b1[s], d, 64);
            float ob2 = __shfl_xor(b2[s], d, 64);
            b2[s] = fminf(fminf(b2[s], ob2), fmaxf(b1[s], ob1));
            b1[s] = fminf(b1[s], ob1);
        }
    }
    if (l15 == 0) {
        #pragma unroll
        for (int s = 0; s < 16; ++s) {
            int m = wm * 64 + (s >> 2) * 16 + quad * 4 + (s & 3);
            mB1[wn][m] = b1[s];
            mB2[wn][m] = b2[s];
        }
    }
    __syncthreads();
    if (t < 128) {
        float a1 = mB1[0][t], c1 = mB1[1][t];
        float f1 = fminf(a1, c1);
        float f2 = fminf(fminf(mB2[0][t], mB2[1][t]), fmaxf(a1, c1));
        ish[t] = (int)(__float_as_uint(f1) & 511u);
        if (f2 - f1 < MARGIN) {
            int p = atomicAdd(cnt, 1);
            wl[p] = n0 + t;
        }
    }
    __syncthreads();

    // ---- fused gather: 2 threads per position, winner row from L2-hot emb
    {
        int p = t >> 1, half = t & 1;
        int n = n0 + p;
        int b = n >> 12, hw = n & 4095;
        int idx = ish[p];
        const float4* sel = (const float4*)(emb + (size_t)idx * DIM) + half * 16;
        float* ob = out + (size_t)b * DIM * HWX + (size_t)half * 64 * HWX + hw;
        #pragma unroll
        for (int c4 = 0; c4 < 16; ++c4) {
            float4 v = sel[c4];
            ob[(size_t)(4 * c4 + 0) * HWX] = v.x;
            ob[(size_t)(4 * c4 + 1) * HWX] = v.y;
            ob[(size_t)(4 * c4 + 2) * HWX] = v.z;
            ob[(size_t)(4 * c4 + 3) * HWX] = v.w;
        }
    }
}

// ---------------- refine v4: exact rescan of flagged positions, writes out rows --
__global__ __launch_bounds__(256) void refine_kernel(const float* __restrict__ z,
                                                     const float* __restrict__ emb,
                                                     const float* __restrict__ esq,
                                                     const int* __restrict__ wl,
                                                     const int* __restrict__ cnt,
                                                     float* __restrict__ out) {
    __shared__ __align__(16) float zsh[64][132];   // [entry][dim]
    __shared__ __align__(16) float esh[64][132];   // [code][dim], col 128 = esq
    __shared__ float rs[64][16];
    __shared__ int   ri[64][16];
    __shared__ int   nsh[64];
    __shared__ int   ksh[64];

    int t = threadIdx.x, lane = t & 63, wave = t >> 6;
    int te = t & 15, tc = t >> 4;                  // entry group / code group
    int count = *cnt;

    for (int base = blockIdx.x * 64; base < count; base += 256 * 64) {
        for (int j16 = 0; j16 < 16; ++j16) {
            int e = wave * 16 + j16;
            int ge = base + e;
            if (ge > count - 1) ge = count - 1;    // clamp: duplicate entries benign
            int n = wl[ge];
            if (lane == 0) nsh[e] = n;
            int b = n >> 12, hw = n & 4095;
            const float* zp = z + (size_t)b * DIM * HWX + hw;
            zsh[e][lane]      = zp[(size_t)lane * HWX];
            zsh[e][lane + 64] = zp[(size_t)(lane + 64) * HWX];
        }

        float best[4]; int bi[4];
        #pragma unroll
        for (int i = 0; i < 4; ++i) { best[i] = 3.0e38f; bi[i] = 0; }

        for (int tile = 0; tile < 8; ++tile) {
            __syncthreads();    // zsh/nsh ready (tile 0); prev esh reads done (tile>0)
            {   // stage 64 codes x 128 dims fp32, coalesced b128; esq into col 128
                const float4* gsrc = (const float4*)(emb + (size_t)tile * 64 * DIM);
                #pragma unroll
                for (int jj = 0; jj < 8; ++jj) {
                    int f = jj * 256 + t;
                    int k = f >> 5, q = f & 31;
                    float4 v = gsrc[f];
                    *(float4*)&esh[k][q * 4] = v;
                }
                if (t < 64) esh[t][128] = esq[tile * 64 + t];
            }
            __syncthreads();

            float acc[4][4];
            #pragma unroll
            for (int i = 0; i < 4; ++i)
                #pragma unroll
                for (int j = 0; j < 4; ++j) acc[i][j] = 0.f;

            #pragma unroll 4
            for (int c4 = 0; c4 < 32; ++c4) {
                float4 zv[4], ev[4];
                #pragma unroll
                for (int i = 0; i < 4; ++i) zv[i] = *(const float4*)&zsh[te + 16 * i][c4 * 4];
                #pragma unroll
                for (int j = 0; j < 4; ++j) ev[j] = *(const float4*)&esh[tc * 4 + j][c4 * 4];
                #pragma unroll
                for (int i = 0; i < 4; ++i)
                    #pragma unroll
                    for (int j = 0; j < 4; ++j) {
                        acc[i][j] = fmaf(zv[i].x, ev[j].x, acc[i][j]);
                        acc[i][j] = fmaf(zv[i].y, ev[j].y, acc[i][j]);
                        acc[i][j] = fmaf(zv[i].z, ev[j].z, acc[i][j]);
                        acc[i][j] = fmaf(zv[i].w, ev[j].w, acc[i][j]);
                    }
            }
            #pragma unroll
            for (int j = 0; j < 4; ++j) {
                int k = tile * 64 + tc * 4 + j;
                float es = esh[tc * 4 + j][128];
                #pragma unroll
                for (int i = 0; i < 4; ++i) {
                    float s = fmaf(-2.f, acc[i][j], es);
                    if (s < best[i]) { best[i] = s; bi[i] = k; }  // k ascending per thread
                }
            }
        }
        __syncthreads();   // all esh/zsh reads done
        #pragma unroll
        for (int i = 0; i < 4; ++i) { rs[te + 16 * i][tc] = best[i]; ri[te + 16 * i][tc] = bi[i]; }
        __syncthreads();
        if (t < 64) {
            float bs = rs[t][0]; int bk = ri[t][0];
            #pragma unroll
            for (int q = 1; q < 16; ++q) {     // lex (s,k): first-min over all 512 codes
                float s2 = rs[t][q]; int k2 = ri[t][q];
                bool take = (s2 < bs) || (s2 == bs && k2 < bk);
                bs = take ? s2 : bs;
                bk = take ? k2 : bk;
            }
            ksh[t] = bk;
        }
        __syncthreads();
        {   // write corrected rows: 4 threads per entry x 32 dims
            int e = t >> 2, qq = t & 3;
            int n = nsh[e];
            int b = n >> 12, hw = n & 4095;
            int kk = ksh[e];
            const float4* sel = (const float4*)(emb + (size_t)kk * DIM) + qq * 8;
            float* ob = out + (size_t)b * DIM * HWX + (size_t)qq * 32 * HWX + hw;
            #pragma unroll
            for (int c4 = 0; c4 < 8; ++c4) {
                float4 v = sel[c4];
                ob[(size_t)(4 * c4 + 0) * HWX] = v.x;
                ob[(size_t)(4 * c4 + 1) * HWX] = v.y;
                ob[(size_t)(4 * c4 + 2) * HWX] = v.z;
                ob[(size_t)(4 * c4 + 3) * HWX] = v.w;
            }
        }
        __syncthreads();   // protect zsh/nsh/ksh for next grid-stride round
    }
}

// ---------------- legacy fallback (round-1, verified) ----------------
__global__ void esq_kernel(const float* __restrict__ emb, float* __restrict__ e_sq) {
    int k = blockIdx.x * blockDim.x + threadIdx.x;
    if (k < NUM_EMB) {
        const float4* row = (const float4*)(emb + k * DIM);
        float s0 = 0.f, s1 = 0.f, s2 = 0.f, s3 = 0.f;
        #pragma unroll
        for (int c = 0; c < DIM / 4; ++c) {
            float4 v = row[c];
            s0 = fmaf(v.x, v.x, s0); s1 = fmaf(v.y, v.y, s1);
            s2 = fmaf(v.z, v.z, s2); s3 = fmaf(v.w, v.w, s3);
        }
        e_sq[k] = (s0 + s1) + (s2 + s3);
    }
}

__global__ __launch_bounds__(256) void vq_kernel(const float* __restrict__ z,
                                                 const float* __restrict__ emb,
                                                 const float* __restrict__ e_sq,
                                                 float* __restrict__ out) {
    int n = blockIdx.x * 256 + threadIdx.x;
    int b = n >> 12, hw = n & 4095;
    const float* zb = z + (size_t)b * DIM * HWX + hw;
    float zr[DIM];
    #pragma unroll
    for (int c = 0; c < DIM; ++c) zr[c] = zb[(size_t)c * HWX];
    float best = FLT_MAX; int besti = 0;
    for (int k = 0; k < NUM_EMB; ++k) {
        const float4* er = (const float4*)(emb + k * DIM);
        float d0 = 0.f, d1 = 0.f, d2 = 0.f, d3 = 0.f;
        #pragma unroll
        for (int c = 0; c < DIM / 4; ++c) {
            float4 e = er[c];
            d0 = fmaf(zr[4 * c + 0], e.x, d0);
            d1 = fmaf(zr[4 * c + 1], e.y, d1);
            d2 = fmaf(zr[4 * c + 2], e.z, d2);
            d3 = fmaf(zr[4 * c + 3], e.w, d3);
        }
        float s = e_sq[k] - 2.f * ((d0 + d1) + (d2 + d3));
        if (s < best) { best = s; besti = k; }
    }
    float* ob = out + (size_t)b * DIM * HWX + hw;
    const float4* sel = (const float4*)(emb + (size_t)besti * DIM);
    #pragma unroll
    for (int c4 = 0; c4 < DIM / 4; ++c4) {
        float4 v = sel[c4];
        ob[(size_t)(4 * c4 + 0) * HWX] = v.x;
        ob[(size_t)(4 * c4 + 1) * HWX] = v.y;
        ob[(size_t)(4 * c4 + 2) * HWX] = v.z;
        ob[(size_t)(4 * c4 + 3) * HWX] = v.w;
    }
}

extern "C" void kernel_launch(void* const* d_in, const int* in_sizes, int n_in,
                              void* d_out, int out_size, void* d_ws, size_t ws_size,
                              hipStream_t stream) {
    const float* z   = (const float*)d_in[0];   // (32,128,64,64) fp32
    const float* emb = (const float*)d_in[1];   // (512,128) fp32
    float* out = (float*)d_out;

    if (ws_size < WS_NEED) {
        // fallback: verified round-1 path
        float* e_sq = (float*)d_ws;
        esq_kernel<<<(NUM_EMB + 255) / 256, 256, 0, stream>>>(emb, e_sq);
        vq_kernel<<<NPOS / 256, 256, 0, stream>>>(z, emb, e_sq, out);
        return;
    }

    char* ws = (char*)d_ws;
    _Float16* e16 = (_Float16*)(ws + WS_E16);
    float*    esq = (float*)(ws + WS_ESQ);
    int*      wl   = (int*)(ws + WS_WL);
    int*      cnt  = (int*)(ws + WS_CNT);

    prep_kernel<<<2, 256, 0, stream>>>(emb, e16, esq, cnt);
    gemm_argmin<<<NPOS / 128, 256, 0, stream>>>(z, e16, esq, emb, out, wl, cnt);
    refine_kernel<<<256, 256, 0, stream>>>(z, emb, esq, wl, cnt, out);
}